// Round 1
// baseline (975.810 us; speedup 1.0000x reference)
//
#include <hip/hip_runtime.h>

__device__ __forceinline__ float sigf(float v) {
    return 1.0f / (1.0f + __expf(-v));
}
__device__ __forceinline__ float tanh_fast(float v) {
    // tanh(v) = 1 - 2/(exp(2v)+1); exact at +-inf, ~1e-6 abs error
    return 1.0f - 2.0f / (__expf(2.0f * v) + 1.0f);
}

// One thread per batch element. Weights are indexed only by loop constants ->
// wave-uniform -> SMEM (s_load) path; H is streamed per-lane with explicit
// double-buffered float4 loads.
__global__ __launch_bounds__(256, 1)
void organism_fused(const float* __restrict__ x,
                    const float* __restrict__ H,
                    const float* __restrict__ W_bit,
                    const float* __restrict__ b_bit,
                    const float* __restrict__ W_bridge,
                    const float* __restrict__ W_read,
                    const float* __restrict__ b_read,
                    const float* __restrict__ W_sh,
                    const float* __restrict__ b_sh,
                    const float* __restrict__ W_eng,
                    const float* __restrict__ b_eng,
                    const float* __restrict__ W_imp,
                    const float* __restrict__ b_imp,
                    const float* __restrict__ W_sur,
                    const float* __restrict__ b_sur,
                    const float* __restrict__ W_gate,
                    const float* __restrict__ b_gate,
                    const float* __restrict__ decays,
                    const float* __restrict__ halt_w,
                    const float* __restrict__ halt_b,
                    float* __restrict__ out)
{
    const int b = blockIdx.x * 256 + threadIdx.x;

    // ================= phase A: small network (term2) =================
    float xv[8];
    {
        const float4 x0 = *(const float4*)(x + (size_t)b * 8);
        const float4 x1 = *(const float4*)(x + (size_t)b * 8 + 4);
        xv[0]=x0.x; xv[1]=x0.y; xv[2]=x0.z; xv[3]=x0.w;
        xv[4]=x1.x; xv[5]=x1.y; xv[6]=x1.z; xv[7]=x1.w;
    }

    float s1[32];
#pragma unroll
    for (int i = 0; i < 32; ++i) {
        float a = b_bit[i];
#pragma unroll
        for (int k = 0; k < 8; ++k) a += W_bit[i*8+k] * xv[k];
        s1[i] = a;
    }

    float sa = b_sur[0], ga = b_gate[0];
#pragma unroll
    for (int i = 0; i < 32; ++i) {
        sa += W_sur[i]  * s1[i];
        ga += W_gate[i] * s1[i];
    }
    const float sur = sigf(sa) * sigf(ga);

    float s2[64];
#pragma unroll
    for (int m = 0; m < 64; ++m) {
        float a = 0.0f;
#pragma unroll
        for (int i = 0; i < 32; ++i) a += W_bridge[m*32+i] * s1[i];
        s2[m] = tanh_fast(a);
    }

    // hg fused into the eng/imp dot products (hg never stored)
    float ea = b_eng[0], ia = b_imp[0];
    for (int n = 0; n < 64; ++n) {
        float a = b_sh[n];
#pragma unroll
        for (int m = 0; m < 64; ++m) a += W_sh[n*64+m] * s2[m];
        a = fmaxf(a, 0.0f);
        ea += W_eng[n] * a;
        ia += W_imp[n] * a;
    }
    const float ei = sigf(ea) * sigf(ia);

    float wv[64];
#pragma unroll
    for (int m = 0; m < 64; ++m) wv[m] = sur * s2[m];

    float out2[8] = {0,0,0,0,0,0,0,0};
    for (int r = 0; r < 8; ++r) {
        float hs = 0.0f;
#pragma unroll
        for (int l = 0; l < 4; ++l) {
            float a = halt_b[l];
#pragma unroll
            for (int m = 0; m < 64; ++m) a += halt_w[(l*8+r)*64+m] * s2[m];
            hs += sigf(a);
        }
        const float gr = 0.25f * ei * hs;   // (1/L) * eng*imp * sum_l halt
#pragma unroll
        for (int o = 0; o < 8; ++o) {
            float p = 0.0f;
#pragma unroll
            for (int m = 0; m < 64; ++m) p += W_read[o*512 + r*64 + m] * wv[m];
            out2[o] += gr * p;
        }
    }

    // ================= phase B: stream H (term1) =================
    const float* __restrict__ Hrow = H + (size_t)b * 2048;
    float acc[8] = {0,0,0,0,0,0,0,0};

    // wave-uniform rotation so concurrent waves hit different channel phases
    const int wid = blockIdx.x * 4 + (threadIdx.x >> 6);
    const int rot = (wid & 7) << 6;          // 0..448, multiple of 8

    float4 hA[4][2], hB[4][2];

    auto loadblk = [&](float4 (&h)[4][2], int ib) {
        const int rmb = ((ib << 3) + rot) & 511;
#pragma unroll
        for (int l = 0; l < 4; ++l) {
            h[l][0] = *(const float4*)(Hrow + l*512 + rmb);
            h[l][1] = *(const float4*)(Hrow + l*512 + rmb + 4);
        }
    };
    auto compute = [&](const float4 (&h)[4][2], int ib) {
        const int rmb = ((ib << 3) + rot) & 511;
        float s[8] = {0,0,0,0,0,0,0,0};
#pragma unroll
        for (int l = 0; l < 4; ++l) {
#pragma unroll
            for (int q = 0; q < 2; ++q) {
                const float4 d = *(const float4*)(decays + l*512 + rmb + q*4); // uniform -> s_load
                const float4 hh = h[l][q];
                s[q*4+0] += sigf(d.x) * hh.x;
                s[q*4+1] += sigf(d.y) * hh.y;
                s[q*4+2] += sigf(d.z) * hh.z;
                s[q*4+3] += sigf(d.w) * hh.w;
            }
        }
#pragma unroll
        for (int c = 0; c < 8; ++c) s[c] *= 0.25f;
#pragma unroll
        for (int o = 0; o < 8; ++o) {
#pragma unroll
            for (int q = 0; q < 2; ++q) {
                const float4 wr = *(const float4*)(W_read + o*512 + rmb + q*4); // uniform -> s_load
                acc[o] += wr.x*s[q*4+0] + wr.y*s[q*4+1]
                        + wr.z*s[q*4+2] + wr.w*s[q*4+3];
            }
        }
    };

    // 64 blocks of 8 floats per l-stream, explicit 1-deep double buffering
    loadblk(hA, 0);
#pragma unroll 1
    for (int p = 0; p < 32; ++p) {
        loadblk(hB, 2*p + 1);
        compute(hA, 2*p);
        if (p + 1 < 32) loadblk(hA, 2*p + 2);
        compute(hB, 2*p + 1);
    }

    // ================= epilogue =================
    float4 r0, r1;
    r0.x = acc[0] + out2[0] + b_read[0];
    r0.y = acc[1] + out2[1] + b_read[1];
    r0.z = acc[2] + out2[2] + b_read[2];
    r0.w = acc[3] + out2[3] + b_read[3];
    r1.x = acc[4] + out2[4] + b_read[4];
    r1.y = acc[5] + out2[5] + b_read[5];
    r1.z = acc[6] + out2[6] + b_read[6];
    r1.w = acc[7] + out2[7] + b_read[7];
    *(float4*)(out + (size_t)b * 8)     = r0;
    *(float4*)(out + (size_t)b * 8 + 4) = r1;
}

extern "C" void kernel_launch(void* const* d_in, const int* in_sizes, int n_in,
                              void* d_out, int out_size, void* d_ws, size_t ws_size,
                              hipStream_t stream) {
    (void)n_in; (void)d_ws; (void)ws_size; (void)out_size;
    const float* x        = (const float*)d_in[0];
    const float* H        = (const float*)d_in[1];
    const float* W_bit    = (const float*)d_in[2];
    const float* b_bit    = (const float*)d_in[3];
    const float* W_bridge = (const float*)d_in[4];
    const float* W_read   = (const float*)d_in[5];
    const float* b_read   = (const float*)d_in[6];
    const float* W_sh     = (const float*)d_in[7];
    const float* b_sh     = (const float*)d_in[8];
    const float* W_eng    = (const float*)d_in[9];
    const float* b_eng    = (const float*)d_in[10];
    const float* W_imp    = (const float*)d_in[11];
    const float* b_imp    = (const float*)d_in[12];
    const float* W_sur    = (const float*)d_in[13];
    const float* b_sur    = (const float*)d_in[14];
    const float* W_gate   = (const float*)d_in[15];
    const float* b_gate   = (const float*)d_in[16];
    const float* decays   = (const float*)d_in[17];
    const float* halt_w   = (const float*)d_in[18];
    const float* halt_b   = (const float*)d_in[19];
    float* out = (float*)d_out;

    const int B = in_sizes[1] / 2048;        // H is [B, 4*8*16*4]
    dim3 grid(B / 256), block(256);
    hipLaunchKernelGGL(organism_fused, grid, block, 0, stream,
                       x, H, W_bit, b_bit, W_bridge, W_read, b_read,
                       W_sh, b_sh, W_eng, b_eng, W_imp, b_imp,
                       W_sur, b_sur, W_gate, b_gate, decays, halt_w, halt_b,
                       out);
}